// Round 7
// baseline (1723.551 us; speedup 1.0000x reference)
//
#include <hip/hip_runtime.h>
#include <stdint.h>

#define BB 8
#define NN 4096
#define CC 64
#define MM 1024
#define EE (BB*MM)   // 8192 centroids
#define KK 64        // max neighbors
#define F3 256       // output channels
#define SM 104       // msg LDS stride (elements), 16B-aligned rows
#define SH 136       // h LDS stride (elements), 16B-aligned rows
#define CAP 768      // candidate buffer
#define NPREP 120    // weight-prep blocks

typedef __bf16 bf16x8 __attribute__((ext_vector_type(8)));
typedef float floatx4 __attribute__((ext_vector_type(4)));
typedef float floatx2 __attribute__((ext_vector_type(2)));

// ---- wave64 reductions via DPP ----
#define DPP_MAXSTEP(ctrl, rmask) { \
    unsigned o = (unsigned)__builtin_amdgcn_update_dpp(0, (int)v, ctrl, rmask, 0xf, false); \
    v = v > o ? v : o; }
__device__ __forceinline__ unsigned wave_umax_u32(unsigned v) {
  DPP_MAXSTEP(0x111, 0xf)
  DPP_MAXSTEP(0x112, 0xf)
  DPP_MAXSTEP(0x114, 0xf)
  DPP_MAXSTEP(0x118, 0xf)
  DPP_MAXSTEP(0x142, 0xa)
  DPP_MAXSTEP(0x143, 0xc)
  return (unsigned)__builtin_amdgcn_readlane((int)v, 63);
}
#define DPP_MINSTEP(ctrl, rmask) { \
    unsigned o = (unsigned)__builtin_amdgcn_update_dpp((int)0xffffffffu, (int)v, ctrl, rmask, 0xf, false); \
    v = v < o ? v : o; }
__device__ __forceinline__ unsigned wave_umin_u32(unsigned v) {
  DPP_MINSTEP(0x111, 0xf)
  DPP_MINSTEP(0x112, 0xf)
  DPP_MINSTEP(0x114, 0xf)
  DPP_MINSTEP(0x118, 0xf)
  DPP_MINSTEP(0x142, 0xa)
  DPP_MINSTEP(0x143, 0xc)
  return (unsigned)__builtin_amdgcn_readlane((int)v, 63);
}

// One fused kernel. Atomic ticket: first 8 executing blocks -> FPS producers
// (one per graph); next 120 -> weight prep; rest -> per-centroid MLP consumers
// that spin on agent-scope progress flags. Consumer e maps g=e&7, m=e>>3 so the
// resident window spans all graphs.
__global__ __launch_bounds__(512, 6) void fused_kernel(
    const float* __restrict__ x, const float* __restrict__ pos,
    const float* __restrict__ W1, const float* __restrict__ b1,
    const float* __restrict__ W2, const float* __restrict__ b2,
    const float* __restrict__ W3, const float* __restrict__ b3,
    unsigned* __restrict__ flags,   // [0]=ticket, [1]=prepDone, [2..9]=prog[g]
    int* __restrict__ fpsIdx, float* __restrict__ ctr,
    __bf16* __restrict__ W1t, __bf16* __restrict__ W2t, __bf16* __restrict__ W3t,
    float* __restrict__ outX, float* __restrict__ outP,
    float* __restrict__ outB, float* __restrict__ outS) {
  __shared__ __align__(16) __bf16 sMsg[64 * SM];   // 13312 B (overlays sDI)
  __shared__ __align__(16) __bf16 sH[64 * SH];     // 17408 B
  __shared__ int sSel[KK];
  __shared__ int sCnt;
  __shared__ unsigned long long sRedK[2][8];
  __shared__ __align__(16) float4 sRedP[2][8];
  __shared__ int sTicket;

  const int t = threadIdx.x;
  const int lane = t & 63, wv = t >> 6;
  if (t == 0)
    sTicket = (int)__hip_atomic_fetch_add(&flags[0], 1u, __ATOMIC_RELAXED,
                                          __HIP_MEMORY_SCOPE_AGENT);
  __syncthreads();
  const int tk = sTicket;

  // ================= FPS producer =================
  if (tk < BB) {
    __builtin_amdgcn_s_setprio(3);
    const int g = tk;
    floatx2 p2x[4], p2y[4], p2z[4];
    float mind[8];
#pragma unroll
    for (int q = 0; q < 4; ++q) {
#pragma unroll
      for (int h = 0; h < 2; ++h) {
        const int p = t + (((q << 1) | h) << 9);
        const long base = ((long)g * NN + p) * 3;
        p2x[q][h] = pos[base + 0];
        p2y[q][h] = pos[base + 1];
        p2z[q][h] = pos[base + 2];
        mind[(q << 1) | h] = 1e10f;
      }
    }
    float wx = pos[(long)g * NN * 3 + 0];
    float wy = pos[(long)g * NN * 3 + 1];
    float wz = pos[(long)g * NN * 3 + 2];
    int winI0 = 0, winI1 = 0;
    float w0x = wx, w0y = wy, w0z = wz;     // seed (step 0) = point 0
    float w1x = wx, w1y = wy, w1z = wz;

    for (int s = 1; s < MM; ++s) {
      const float nwx = -wx, nwy = -wy, nwz = -wz;
      const floatx2 nx2 = {nwx, nwx}, ny2 = {nwy, nwy}, nz2 = {nwz, nwz};
      unsigned bb = 0u, bidx = (unsigned)t;
#pragma unroll
      for (int q = 0; q < 4; ++q) {
        floatx2 dx, dy, dz, xx, yy, zz, s1, d2;
        asm("v_pk_add_f32 %0, %1, %2" : "=v"(dx) : "v"(p2x[q]), "v"(nx2));
        asm("v_pk_add_f32 %0, %1, %2" : "=v"(dy) : "v"(p2y[q]), "v"(ny2));
        asm("v_pk_add_f32 %0, %1, %2" : "=v"(dz) : "v"(p2z[q]), "v"(nz2));
        asm("v_pk_mul_f32 %0, %1, %1" : "=v"(xx) : "v"(dx));
        asm("v_pk_mul_f32 %0, %1, %1" : "=v"(yy) : "v"(dy));
        asm("v_pk_mul_f32 %0, %1, %1" : "=v"(zz) : "v"(dz));
        asm("v_pk_add_f32 %0, %1, %2" : "=v"(s1) : "v"(xx), "v"(yy));
        asm("v_pk_add_f32 %0, %1, %2" : "=v"(d2) : "v"(s1), "v"(zz));
#pragma unroll
        for (int h = 0; h < 2; ++h) {
          const int i = (q << 1) | h;
          mind[i] = fminf(mind[i], d2[h]);
          const unsigned mb = __float_as_uint(mind[i]);
          if (mb > bb) { bb = mb; bidx = (unsigned)(t + (i << 9)); }
        }
      }
      const unsigned maxv = wave_umax_u32(bb);
      const unsigned cand = (bb == maxv) ? bidx : 0xffffffffu;
      const unsigned minidx = wave_umin_u32(cand);
      // wave-winner xyz: select slot, then broadcast from winning lane
      const int jw = (int)(minidx >> 9), qw = jw >> 1, hw = jw & 1;
      const floatx2 sx = p2x[qw], sy = p2y[qw], sz = p2z[qw];
      const float cxx = hw ? sx[1] : sx[0];
      const float cyy = hw ? sy[1] : sy[0];
      const float czz = hw ? sz[1] : sz[0];
      const int lw = (int)(minidx & 63u);
      const float bx = __int_as_float(__builtin_amdgcn_readlane(__float_as_int(cxx), lw));
      const float by = __int_as_float(__builtin_amdgcn_readlane(__float_as_int(cyy), lw));
      const float bz = __int_as_float(__builtin_amdgcn_readlane(__float_as_int(czz), lw));
      if (lane == 0) {
        sRedK[s & 1][wv] = ((unsigned long long)maxv << 32) |
                           (unsigned long long)(~minidx);
        sRedP[s & 1][wv] = make_float4(bx, by, bz, 0.0f);
      }
      __syncthreads();
      unsigned long long kk = sRedK[s & 1][0];
      int wbest = 0;
#pragma unroll
      for (int w = 1; w < 8; ++w) {
        const unsigned long long kw = sRedK[s & 1][w];
        if (kw > kk) { kk = kw; wbest = w; }
      }
      const float4 wp = sRedP[s & 1][wbest];
      wx = wp.x; wy = wp.y; wz = wp.z;
      const int widx = (int)(~(unsigned)kk);
      if (s == t)       { winI0 = widx; w0x = wx; w0y = wy; w0z = wz; }
      if (s == t + 512) { winI1 = widx; w1x = wx; w1y = wy; w1z = wz; }
      if ((s & 63) == 63) {
        const int f = s >> 6;                 // 0..15
        if (wv == (f & 7)) {
          const int step = (f < 8) ? t : (t + 512);
          const int wI   = (f < 8) ? winI0 : winI1;
          const float fx = (f < 8) ? w0x : w1x;
          const float fy = (f < 8) ? w0y : w1y;
          const float fz = (f < 8) ? w0z : w1z;
          const long ee = (long)g * MM + step;
          __hip_atomic_store(&fpsIdx[ee], wI, __ATOMIC_RELAXED, __HIP_MEMORY_SCOPE_AGENT);
          __hip_atomic_store(&ctr[ee * 3 + 0], fx, __ATOMIC_RELAXED, __HIP_MEMORY_SCOPE_AGENT);
          __hip_atomic_store(&ctr[ee * 3 + 1], fy, __ATOMIC_RELAXED, __HIP_MEMORY_SCOPE_AGENT);
          __hip_atomic_store(&ctr[ee * 3 + 2], fz, __ATOMIC_RELAXED, __HIP_MEMORY_SCOPE_AGENT);
          if (lane == 0)
            __hip_atomic_store(&flags[2 + g], (unsigned)((f + 1) * 64),
                               __ATOMIC_RELEASE, __HIP_MEMORY_SCOPE_AGENT);
        }
      }
    }
    return;
  }

  // ================= weight prep =================
  if (tk < BB + NPREP) {
    const int i0 = (tk - BB) * 512 + t;
    if (i0 < 128 * 96) {
      const int n = i0 / 96, k = i0 % 96;
      W1t[i0] = (k < 67) ? (__bf16)W1[k * 128 + n] : (__bf16)0.0f;
    } else if (i0 < 128 * 96 + 128 * 128) {
      const int i = i0 - 128 * 96;
      const int n = i / 128, k = i % 128;
      W2t[i] = (__bf16)W2[k * 128 + n];
    } else {
      const int i = i0 - (128 * 96 + 128 * 128);
      const int n = i / 128, k = i % 128;
      W3t[i] = (__bf16)W3[k * 256 + n];
    }
    __syncthreads();
    if (t == 0)
      __hip_atomic_fetch_add(&flags[1], 1u, __ATOMIC_RELEASE, __HIP_MEMORY_SCOPE_AGENT);
    return;
  }

  // ================= MLP consumer =================
  const int eo = tk - (BB + NPREP);
  const int b = eo & 7;            // graph
  const int m = eo >> 3;           // centroid within graph
  const int e = b * MM + m;        // output row

  if (t == 1) sCnt = 0;
  if (t == 0) {
    while (__hip_atomic_load(&flags[1], __ATOMIC_RELAXED, __HIP_MEMORY_SCOPE_AGENT) < NPREP)
      __builtin_amdgcn_s_sleep(32);
    while ((int)__hip_atomic_load(&flags[2 + b], __ATOMIC_RELAXED, __HIP_MEMORY_SCOPE_AGENT) <= m)
      __builtin_amdgcn_s_sleep(32);
    (void)__hip_atomic_load(&flags[1], __ATOMIC_ACQUIRE, __HIP_MEMORY_SCOPE_AGENT);
    (void)__hip_atomic_load(&flags[2 + b], __ATOMIC_ACQUIRE, __HIP_MEMORY_SCOPE_AGENT);
  }
  __syncthreads();

  unsigned long long* sDI = (unsigned long long*)sMsg;  // [CAP] (d2bits<<32|idx)
  const float cx = ctr[(long)e * 3 + 0];
  const float cy = ctr[(long)e * 3 + 1];
  const float cz = ctr[(long)e * 3 + 2];
  if (t < 3) outP[(long)e * 3 + t] = ctr[(long)e * 3 + t];
  if (t == 3) { outB[e] = (float)b; outS[e] = (float)(b * NN + fpsIdx[e]); }
  const float R2 = (float)(0.2 * 0.2);
  const long pbase = (long)b * NN * 3;

  // Phase A: scan 4096 points; ballot-compact candidates into LDS.
#pragma unroll
  for (int q = 0; q < NN / 512; ++q) {
    const int p = t + q * 512;
    const float dx = __fsub_rn(cx, pos[pbase + (long)p * 3 + 0]);
    const float dy = __fsub_rn(cy, pos[pbase + (long)p * 3 + 1]);
    const float dz = __fsub_rn(cz, pos[pbase + (long)p * 3 + 2]);
    const float d2 = __fadd_rn(__fadd_rn(__fmul_rn(dx, dx), __fmul_rn(dy, dy)), __fmul_rn(dz, dz));
    const bool v = d2 < R2;
    const unsigned long long mask = __ballot(v);
    int wbase = 0;
    if (lane == 0 && mask) wbase = atomicAdd(&sCnt, (int)__popcll(mask));
    wbase = __shfl(wbase, 0);
    if (v) {
      const int off = wbase + (int)__popcll(mask & ((1ull << lane) - 1ull));
      if (off < CAP)
        sDI[off] = ((unsigned long long)__float_as_uint(d2) << 32) | (unsigned)p;
    }
  }
  __syncthreads();
  int cnt = sCnt; cnt = cnt > CAP ? CAP : cnt;
  const int nsel = cnt < KK ? cnt : KK;

  // Phase B: parallel rank selection (rank = #smaller keys; keep rank<K).
  for (int i = t; i < cnt; i += 512) {
    const unsigned long long my = sDI[i];
    int rank = 0;
#pragma unroll 8
    for (int j = 0; j < cnt; ++j) rank += (sDI[j] < my) ? 1 : 0;
    if (rank < KK) sSel[rank] = (int)(unsigned)(my & 0xffffffffu);
  }
  __syncthreads();
  cnt = nsel;

  // Phase C: stage msg tile [64 x (64 feat | 3 dpos | pad)] as bf16.
  {
    const int r = t >> 3, p = t & 7;
    float4 a = make_float4(0.f, 0.f, 0.f, 0.f), c4 = a;
    if (r < cnt) {
      const float* xr = x + (long)(b * NN + sSel[r]) * CC + p * 8;
      a  = *(const float4*)xr;
      c4 = *(const float4*)(xr + 4);
    }
    __bf16 o[8] = {(__bf16)a.x, (__bf16)a.y, (__bf16)a.z, (__bf16)a.w,
                   (__bf16)c4.x, (__bf16)c4.y, (__bf16)c4.z, (__bf16)c4.w};
    __syncthreads();  // Phase-B reads of sDI done before overwrite
    *(uint4*)&sMsg[r * SM + p * 8] = *(uint4*)o;
  }
  if (t < 64) {
    const int r = t;
    __bf16 d0 = (__bf16)0.0f, d1 = (__bf16)0.0f, d2v = (__bf16)0.0f;
    if (r < cnt) {
      const long j = pbase + (long)sSel[r] * 3;
      d0  = (__bf16)__fsub_rn(pos[j + 0], cx);
      d1  = (__bf16)__fsub_rn(pos[j + 1], cy);
      d2v = (__bf16)__fsub_rn(pos[j + 2], cz);
    }
    sMsg[r * SM + 64] = d0;
    sMsg[r * SM + 65] = d1;
    sMsg[r * SM + 66] = d2v;
    for (int c = 67; c < SM; ++c) sMsg[r * SM + c] = (__bf16)0.0f;
  }
  __syncthreads();

  const int l15 = lane & 15, quad = lane >> 4;
  // ---- layer 1: [64 x 96] @ [96 x 128] -> sH ----
  {
    floatx4 acc[4] = {};
    const __bf16* wrow = W1t + (wv * 16 + l15) * 96;
#pragma unroll
    for (int ks = 0; ks < 3; ++ks) {
      const bf16x8 bfrag = *(const bf16x8*)(wrow + ks * 32 + quad * 8);
#pragma unroll
      for (int mt = 0; mt < 4; ++mt) {
        const bf16x8 afrag = *(const bf16x8*)&sMsg[(mt * 16 + l15) * SM + ks * 32 + quad * 8];
        acc[mt] = __builtin_amdgcn_mfma_f32_16x16x32_bf16(afrag, bfrag, acc[mt], 0, 0, 0);
      }
    }
    const int col = wv * 16 + l15;
    const float bias = b1[col];
#pragma unroll
    for (int mt = 0; mt < 4; ++mt)
#pragma unroll
      for (int rg = 0; rg < 4; ++rg) {
        const int row = mt * 16 + quad * 4 + rg;
        float v = acc[mt][rg] + bias;
        v = v > 0.0f ? v : 0.0f;
        sH[row * SH + col] = (__bf16)v;
      }
  }
  __syncthreads();
  // ---- layer 2: [64 x 128] @ [128 x 128], IN PLACE on sH ----
  {
    floatx4 acc[4] = {};
    const __bf16* wrow = W2t + (wv * 16 + l15) * 128;
#pragma unroll
    for (int ks = 0; ks < 4; ++ks) {
      const bf16x8 bfrag = *(const bf16x8*)(wrow + ks * 32 + quad * 8);
#pragma unroll
      for (int mt = 0; mt < 4; ++mt) {
        const bf16x8 afrag = *(const bf16x8*)&sH[(mt * 16 + l15) * SH + ks * 32 + quad * 8];
        acc[mt] = __builtin_amdgcn_mfma_f32_16x16x32_bf16(afrag, bfrag, acc[mt], 0, 0, 0);
      }
    }
    __syncthreads();
    const int col = wv * 16 + l15;
    const float bias = b2[col];
#pragma unroll
    for (int mt = 0; mt < 4; ++mt)
#pragma unroll
      for (int rg = 0; rg < 4; ++rg) {
        const int row = mt * 16 + quad * 4 + rg;
        float v = acc[mt][rg] + bias;
        v = v > 0.0f ? v : 0.0f;
        sH[row * SH + col] = (__bf16)v;
      }
  }
  __syncthreads();
  // ---- layer 3: [64 x 128] @ [128 x 256]; fused masked column max ----
  {
    floatx4 acc[2][4] = {};
#pragma unroll
    for (int ks = 0; ks < 4; ++ks) {
      bf16x8 afrag[4];
#pragma unroll
      for (int mt = 0; mt < 4; ++mt)
        afrag[mt] = *(const bf16x8*)&sH[(mt * 16 + l15) * SH + ks * 32 + quad * 8];
#pragma unroll
      for (int i = 0; i < 2; ++i) {
        const bf16x8 bfrag = *(const bf16x8*)(W3t + ((wv * 2 + i) * 16 + l15) * 128 + ks * 32 + quad * 8);
#pragma unroll
        for (int mt = 0; mt < 4; ++mt)
          acc[i][mt] = __builtin_amdgcn_mfma_f32_16x16x32_bf16(afrag[mt], bfrag, acc[i][mt], 0, 0, 0);
      }
    }
#pragma unroll
    for (int i = 0; i < 2; ++i) {
      const int col = (wv * 2 + i) * 16 + l15;
      const float bias = b3[col];
      float mx = 0.0f;  // centroid itself in-radius => cnt>=1; ReLU >= 0
#pragma unroll
      for (int mt = 0; mt < 4; ++mt)
#pragma unroll
        for (int rg = 0; rg < 4; ++rg) {
          const int row = mt * 16 + quad * 4 + rg;
          float v = acc[i][mt][rg] + bias;
          v = v > 0.0f ? v : 0.0f;
          if (row < cnt) mx = fmaxf(mx, v);
        }
      mx = fmaxf(mx, __shfl_xor(mx, 16));
      mx = fmaxf(mx, __shfl_xor(mx, 32));
      if (quad == 0) outX[(long)e * F3 + col] = mx;
    }
  }
}

extern "C" void kernel_launch(void* const* d_in, const int* in_sizes, int n_in,
                              void* d_out, int out_size, void* d_ws, size_t ws_size,
                              hipStream_t stream) {
  const float* x   = (const float*)d_in[0];
  const float* pos = (const float*)d_in[1];
  const float* W1  = (const float*)d_in[4];
  const float* b1  = (const float*)d_in[5];
  const float* W2  = (const float*)d_in[6];
  const float* b2  = (const float*)d_in[7];
  const float* W3  = (const float*)d_in[8];
  const float* b3  = (const float*)d_in[9];

  // Workspace (~255 KB)
  char* ws = (char*)d_ws;
  unsigned* flags  = (unsigned*)(ws);          // 64 B: ticket, prepDone, prog[8]
  int*    fpsIdx = (int*)(ws + 1024);          // 32768   (ends 33792)
  float*  ctr    = (float*)(ws + 33792);       // 98304   (ends 132096)
  __bf16* W1t    = (__bf16*)(ws + 132096);     // 24576   (ends 156672)
  __bf16* W2t    = (__bf16*)(ws + 156672);     // 32768   (ends 189440)
  __bf16* W3t    = (__bf16*)(ws + 189440);     // 65536   (ends 254976)

  float* outX = (float*)d_out;                 // [8192,256]
  float* outP = outX + (long)EE * F3;          // [8192,3]
  float* outB = outP + (long)EE * 3;           // [8192]
  float* outS = outB + EE;                     // [8192]

  hipMemsetAsync(flags, 0, 64, stream);
  fused_kernel<<<BB + NPREP + EE, 512, 0, stream>>>(
      x, pos, W1, b1, W2, b2, W3, b3,
      flags, fpsIdx, ctr, W1t, W2t, W3t, outX, outP, outB, outS);
}

// Round 8
// 1284.958 us; speedup vs baseline: 1.3413x; 1.3413x over previous
//
#include <hip/hip_runtime.h>
#include <stdint.h>

#define BB 8
#define NN 4096
#define CC 64
#define MM 1024
#define EE (BB*MM)   // 8192 centroids
#define KK 64        // max neighbors
#define F3 256       // output channels
#define SM 104       // msg LDS stride (elements), 16B-aligned rows
#define SH 136       // h LDS stride (elements), 16B-aligned rows
#define CAP 768      // candidate buffer

typedef __bf16 bf16x8 __attribute__((ext_vector_type(8)));
typedef float floatx4 __attribute__((ext_vector_type(4)));
typedef float floatx2 __attribute__((ext_vector_type(2)));

// ---- wave64 reductions via DPP ----
#define DPP_MAXSTEP(ctrl, rmask) { \
    unsigned o = (unsigned)__builtin_amdgcn_update_dpp(0, (int)v, ctrl, rmask, 0xf, false); \
    v = v > o ? v : o; }
__device__ __forceinline__ unsigned wave_umax_u32(unsigned v) {
  DPP_MAXSTEP(0x111, 0xf)
  DPP_MAXSTEP(0x112, 0xf)
  DPP_MAXSTEP(0x114, 0xf)
  DPP_MAXSTEP(0x118, 0xf)
  DPP_MAXSTEP(0x142, 0xa)
  DPP_MAXSTEP(0x143, 0xc)
  return (unsigned)__builtin_amdgcn_readlane((int)v, 63);
}
#define DPP_MINSTEP(ctrl, rmask) { \
    unsigned o = (unsigned)__builtin_amdgcn_update_dpp((int)0xffffffffu, (int)v, ctrl, rmask, 0xf, false); \
    v = v < o ? v : o; }
__device__ __forceinline__ unsigned wave_umin_u32(unsigned v) {
  DPP_MINSTEP(0x111, 0xf)
  DPP_MINSTEP(0x112, 0xf)
  DPP_MINSTEP(0x114, 0xf)
  DPP_MINSTEP(0x118, 0xf)
  DPP_MINSTEP(0x142, 0xa)
  DPP_MINSTEP(0x143, 0xc)
  return (unsigned)__builtin_amdgcn_readlane((int)v, 63);
}

// ---- FPS (blocks 0..7, pk-f32 + reg-carried winner xyz) + wprep (8..127) + pos4 (128..191) ----
__global__ __launch_bounds__(512) void fps_prep_kernel(
    const float* __restrict__ pos,
    const float* __restrict__ W1, const float* __restrict__ W2, const float* __restrict__ W3,
    int* __restrict__ fpsIdx, float* __restrict__ ctr,
    __bf16* __restrict__ W1t, __bf16* __restrict__ W2t, __bf16* __restrict__ W3t,
    float4* __restrict__ pos4) {
  __shared__ unsigned long long sRedK[2][8];
  __shared__ __align__(16) float4 sRedP[2][8];
  const int blk = blockIdx.x;
  const int t = threadIdx.x;

  if (blk >= BB) {
    if (blk < 128) {                               // wprep: 61440 elements
      const int i0 = (blk - 8) * 512 + t;
      if (i0 < 128 * 96) {
        const int n = i0 / 96, k = i0 % 96;
        W1t[i0] = (k < 67) ? (__bf16)W1[k * 128 + n] : (__bf16)0.0f;
      } else if (i0 < 128 * 96 + 128 * 128) {
        const int i = i0 - 128 * 96;
        const int n = i / 128, k = i % 128;
        W2t[i] = (__bf16)W2[k * 128 + n];
      } else {
        const int i = i0 - (128 * 96 + 128 * 128);
        const int n = i / 128, k = i % 128;
        W3t[i] = (__bf16)W3[k * 256 + n];
      }
    } else {                                       // posp: 32768 points
      const int i = (blk - 128) * 512 + t;
      pos4[i] = make_float4(pos[(long)i * 3 + 0], pos[(long)i * 3 + 1],
                            pos[(long)i * 3 + 2], 0.0f);
    }
    return;
  }

  const int g = blk;
  const int lane = t & 63, wv = t >> 6;
  floatx2 p2x[4], p2y[4], p2z[4];
  float mind[8];
#pragma unroll
  for (int q = 0; q < 4; ++q) {
#pragma unroll
    for (int h = 0; h < 2; ++h) {
      const int p = t + (((q << 1) | h) << 9);
      const long base = ((long)g * NN + p) * 3;
      p2x[q][h] = pos[base + 0];
      p2y[q][h] = pos[base + 1];
      p2z[q][h] = pos[base + 2];
      mind[(q << 1) | h] = 1e10f;
    }
  }
  float wx = pos[(long)g * NN * 3 + 0];
  float wy = pos[(long)g * NN * 3 + 1];
  float wz = pos[(long)g * NN * 3 + 2];
  int winI0 = 0, winI1 = 0;
  float w0x = wx, w0y = wy, w0z = wz;     // seed (step 0) = point 0
  float w1x = wx, w1y = wy, w1z = wz;

  for (int s = 1; s < MM; ++s) {
    const float nwx = -wx, nwy = -wy, nwz = -wz;
    const floatx2 nx2 = {nwx, nwx}, ny2 = {nwy, nwy}, nz2 = {nwz, nwz};
    unsigned bb = 0u, bidx = (unsigned)t;
#pragma unroll
    for (int q = 0; q < 4; ++q) {
      floatx2 dx, dy, dz, xx, yy, zz, s1, d2;
      asm("v_pk_add_f32 %0, %1, %2" : "=v"(dx) : "v"(p2x[q]), "v"(nx2));
      asm("v_pk_add_f32 %0, %1, %2" : "=v"(dy) : "v"(p2y[q]), "v"(ny2));
      asm("v_pk_add_f32 %0, %1, %2" : "=v"(dz) : "v"(p2z[q]), "v"(nz2));
      asm("v_pk_mul_f32 %0, %1, %1" : "=v"(xx) : "v"(dx));
      asm("v_pk_mul_f32 %0, %1, %1" : "=v"(yy) : "v"(dy));
      asm("v_pk_mul_f32 %0, %1, %1" : "=v"(zz) : "v"(dz));
      asm("v_pk_add_f32 %0, %1, %2" : "=v"(s1) : "v"(xx), "v"(yy));
      asm("v_pk_add_f32 %0, %1, %2" : "=v"(d2) : "v"(s1), "v"(zz));
#pragma unroll
      for (int h = 0; h < 2; ++h) {
        const int i = (q << 1) | h;
        mind[i] = fminf(mind[i], d2[h]);
        const unsigned mb = __float_as_uint(mind[i]);
        if (mb > bb) { bb = mb; bidx = (unsigned)(t + (i << 9)); }
      }
    }
    const unsigned maxv = wave_umax_u32(bb);
    const unsigned cand = (bb == maxv) ? bidx : 0xffffffffu;
    const unsigned minidx = wave_umin_u32(cand);
    // wave-winner xyz: select slot regs (minidx is wave-uniform), broadcast from its lane
    const int jw = (int)(minidx >> 9), qw = jw >> 1, hw = jw & 1;
    const floatx2 sx = p2x[qw], sy = p2y[qw], sz = p2z[qw];
    const float cxx = hw ? sx[1] : sx[0];
    const float cyy = hw ? sy[1] : sy[0];
    const float czz = hw ? sz[1] : sz[0];
    const int lw = (int)(minidx & 63u);
    const float bx = __int_as_float(__builtin_amdgcn_readlane(__float_as_int(cxx), lw));
    const float by = __int_as_float(__builtin_amdgcn_readlane(__float_as_int(cyy), lw));
    const float bz = __int_as_float(__builtin_amdgcn_readlane(__float_as_int(czz), lw));
    if (lane == 0) {
      sRedK[s & 1][wv] = ((unsigned long long)maxv << 32) |
                         (unsigned long long)(~minidx);
      sRedP[s & 1][wv] = make_float4(bx, by, bz, 0.0f);
    }
    __syncthreads();
    unsigned long long kk = sRedK[s & 1][0];
    int wbest = 0;
#pragma unroll
    for (int w = 1; w < 8; ++w) {
      const unsigned long long kw = sRedK[s & 1][w];
      if (kw > kk) { kk = kw; wbest = w; }
    }
    const float4 wp = sRedP[s & 1][wbest];
    wx = wp.x; wy = wp.y; wz = wp.z;
    const int widx = (int)(~(unsigned)kk);
    if (s == t)       { winI0 = widx; w0x = wx; w0y = wy; w0z = wz; }
    if (s == t + 512) { winI1 = widx; w1x = wx; w1y = wy; w1z = wz; }
  }
  // Epilogue: batched global writes (thread t owns steps t and t+512).
  {
    const long e0 = (long)g * MM + t;
    fpsIdx[e0] = winI0;
    ctr[e0 * 3 + 0] = w0x; ctr[e0 * 3 + 1] = w0y; ctr[e0 * 3 + 2] = w0z;
    const long e1 = e0 + 512;
    fpsIdx[e1] = winI1;
    ctr[e1 * 3 + 0] = w1x; ctr[e1 * 3 + 1] = w1y; ctr[e1 * 3 + 2] = w1z;
  }
}

// ---- Fused radius-search + rank-top-K + gather + 3-layer MLP (MFMA) + masked max ----
__global__ __launch_bounds__(512) void mlp_kernel(const float* __restrict__ x,
    const float4* __restrict__ pos4, const float* __restrict__ ctr,
    const int* __restrict__ fpsIdx,
    const __bf16* __restrict__ W1t, const __bf16* __restrict__ W2t,
    const __bf16* __restrict__ W3t,
    const float* __restrict__ b1, const float* __restrict__ b2,
    const float* __restrict__ b3,
    float* __restrict__ outX, float* __restrict__ outP,
    float* __restrict__ outB, float* __restrict__ outS) {
  __shared__ __align__(16) __bf16 sMsg[64 * SM];   // 13312 B; overlays sDI (6144 B)
  __shared__ __align__(16) __bf16 sH[64 * SH];     // 17408 B
  __shared__ int sSel[KK];
  __shared__ int sCnt;
  unsigned long long* sDI = (unsigned long long*)sMsg;  // [CAP] packed (d2bits<<32 | idx)

  const int e = blockIdx.x;
  const int t = threadIdx.x;
  const int b = e >> 10;
  const int lane = t & 63, wv = t >> 6;

  if (t == 0) sCnt = 0;
  const float cx = ctr[(long)e * 3 + 0];
  const float cy = ctr[(long)e * 3 + 1];
  const float cz = ctr[(long)e * 3 + 2];
  if (t < 3) outP[(long)e * 3 + t] = ctr[(long)e * 3 + t];
  if (t == 3) { outB[e] = (float)b; outS[e] = (float)(b * NN + fpsIdx[e]); }
  const float R2 = (float)(0.2 * 0.2);
  __syncthreads();

  // Phase A: scan 4096 points (float4 loads); ballot-compact candidates to LDS.
#pragma unroll
  for (int q = 0; q < NN / 512; ++q) {
    const int p = t + q * 512;
    const float4 P = pos4[b * NN + p];
    const float dx = __fsub_rn(cx, P.x);
    const float dy = __fsub_rn(cy, P.y);
    const float dz = __fsub_rn(cz, P.z);
    const float d2 = __fadd_rn(__fadd_rn(__fmul_rn(dx, dx), __fmul_rn(dy, dy)), __fmul_rn(dz, dz));
    const bool v = d2 < R2;
    const unsigned long long mask = __ballot(v);
    int wbase = 0;
    if (lane == 0 && mask) wbase = atomicAdd(&sCnt, (int)__popcll(mask));
    wbase = __shfl(wbase, 0);
    if (v) {
      const int off = wbase + (int)__popcll(mask & ((1ull << lane) - 1ull));
      if (off < CAP)
        sDI[off] = ((unsigned long long)__float_as_uint(d2) << 32) | (unsigned)p;
    }
  }
  __syncthreads();
  int cnt = sCnt; cnt = cnt > CAP ? CAP : cnt;
  const int nsel = cnt < KK ? cnt : KK;

  // Phase B: parallel rank selection. rank(i) = #{j : key_j < key_i}; keep rank<K.
  for (int i = t; i < cnt; i += 512) {
    const unsigned long long my = sDI[i];
    int rank = 0;
#pragma unroll 8
    for (int j = 0; j < cnt; ++j) rank += (sDI[j] < my) ? 1 : 0;
    if (rank < KK) sSel[rank] = (int)(unsigned)(my & 0xffffffffu);
  }
  __syncthreads();
  cnt = nsel;

  // Phase C: stage msg tile [64 x (64 feat | 3 dpos | zero-pad)] into LDS as bf16.
  {
    const int r = t >> 3, p = t & 7;
    float4 a = make_float4(0.f, 0.f, 0.f, 0.f), c4 = a;
    if (r < cnt) {
      const float* xr = x + (long)(b * NN + sSel[r]) * CC + p * 8;
      a  = *(const float4*)xr;
      c4 = *(const float4*)(xr + 4);
    }
    __bf16 o[8] = {(__bf16)a.x, (__bf16)a.y, (__bf16)a.z, (__bf16)a.w,
                   (__bf16)c4.x, (__bf16)c4.y, (__bf16)c4.z, (__bf16)c4.w};
    __syncthreads();  // Phase-B reads of sDI done before overwrite
    *(uint4*)&sMsg[r * SM + p * 8] = *(uint4*)o;
  }
  if (t < 64) {
    const int r = t;
    __bf16 d0 = (__bf16)0.0f, d1 = (__bf16)0.0f, d2v = (__bf16)0.0f;
    if (r < cnt) {
      const float4 P = pos4[b * NN + sSel[r]];
      d0  = (__bf16)__fsub_rn(P.x, cx);
      d1  = (__bf16)__fsub_rn(P.y, cy);
      d2v = (__bf16)__fsub_rn(P.z, cz);
    }
    sMsg[r * SM + 64] = d0;
    sMsg[r * SM + 65] = d1;
    sMsg[r * SM + 66] = d2v;
    for (int c = 67; c < SM; ++c) sMsg[r * SM + c] = (__bf16)0.0f;
  }
  __syncthreads();

  const int l15 = lane & 15, quad = lane >> 4;
  // ---- layer 1: [64 x 96] @ [96 x 128] -> sH ----
  {
    floatx4 acc[4] = {};
    const __bf16* wrow = W1t + (wv * 16 + l15) * 96;
#pragma unroll
    for (int ks = 0; ks < 3; ++ks) {
      const bf16x8 bfrag = *(const bf16x8*)(wrow + ks * 32 + quad * 8);
#pragma unroll
      for (int mt = 0; mt < 4; ++mt) {
        const bf16x8 afrag = *(const bf16x8*)&sMsg[(mt * 16 + l15) * SM + ks * 32 + quad * 8];
        acc[mt] = __builtin_amdgcn_mfma_f32_16x16x32_bf16(afrag, bfrag, acc[mt], 0, 0, 0);
      }
    }
    const int col = wv * 16 + l15;
    const float bias = b1[col];
#pragma unroll
    for (int mt = 0; mt < 4; ++mt)
#pragma unroll
      for (int rg = 0; rg < 4; ++rg) {
        const int row = mt * 16 + quad * 4 + rg;
        float v = acc[mt][rg] + bias;
        v = v > 0.0f ? v : 0.0f;
        sH[row * SH + col] = (__bf16)v;
      }
  }
  __syncthreads();
  // ---- layer 2: [64 x 128] @ [128 x 128], IN PLACE on sH ----
  {
    floatx4 acc[4] = {};
    const __bf16* wrow = W2t + (wv * 16 + l15) * 128;
#pragma unroll
    for (int ks = 0; ks < 4; ++ks) {
      const bf16x8 bfrag = *(const bf16x8*)(wrow + ks * 32 + quad * 8);
#pragma unroll
      for (int mt = 0; mt < 4; ++mt) {
        const bf16x8 afrag = *(const bf16x8*)&sH[(mt * 16 + l15) * SH + ks * 32 + quad * 8];
        acc[mt] = __builtin_amdgcn_mfma_f32_16x16x32_bf16(afrag, bfrag, acc[mt], 0, 0, 0);
      }
    }
    __syncthreads();
    const int col = wv * 16 + l15;
    const float bias = b2[col];
#pragma unroll
    for (int mt = 0; mt < 4; ++mt)
#pragma unroll
      for (int rg = 0; rg < 4; ++rg) {
        const int row = mt * 16 + quad * 4 + rg;
        float v = acc[mt][rg] + bias;
        v = v > 0.0f ? v : 0.0f;
        sH[row * SH + col] = (__bf16)v;
      }
  }
  __syncthreads();
  // ---- layer 3: [64 x 128] @ [128 x 256]; fused masked column max ----
  {
    floatx4 acc[2][4] = {};
#pragma unroll
    for (int ks = 0; ks < 4; ++ks) {
      bf16x8 afrag[4];
#pragma unroll
      for (int mt = 0; mt < 4; ++mt)
        afrag[mt] = *(const bf16x8*)&sH[(mt * 16 + l15) * SH + ks * 32 + quad * 8];
#pragma unroll
      for (int i = 0; i < 2; ++i) {
        const bf16x8 bfrag = *(const bf16x8*)(W3t + ((wv * 2 + i) * 16 + l15) * 128 + ks * 32 + quad * 8);
#pragma unroll
        for (int mt = 0; mt < 4; ++mt)
          acc[i][mt] = __builtin_amdgcn_mfma_f32_16x16x32_bf16(afrag[mt], bfrag, acc[i][mt], 0, 0, 0);
      }
    }
#pragma unroll
    for (int i = 0; i < 2; ++i) {
      const int col = (wv * 2 + i) * 16 + l15;
      const float bias = b3[col];
      float mx = 0.0f;  // centroid itself in-radius => cnt>=1; ReLU >= 0
#pragma unroll
      for (int mt = 0; mt < 4; ++mt)
#pragma unroll
        for (int rg = 0; rg < 4; ++rg) {
          const int row = mt * 16 + quad * 4 + rg;
          float v = acc[i][mt][rg] + bias;
          v = v > 0.0f ? v : 0.0f;
          if (row < cnt) mx = fmaxf(mx, v);
        }
      mx = fmaxf(mx, __shfl_xor(mx, 16));
      mx = fmaxf(mx, __shfl_xor(mx, 32));
      if (quad == 0) outX[(long)e * F3 + col] = mx;
    }
  }
}

extern "C" void kernel_launch(void* const* d_in, const int* in_sizes, int n_in,
                              void* d_out, int out_size, void* d_ws, size_t ws_size,
                              hipStream_t stream) {
  const float* x   = (const float*)d_in[0];
  const float* pos = (const float*)d_in[1];
  const float* W1  = (const float*)d_in[4];
  const float* b1  = (const float*)d_in[5];
  const float* W2  = (const float*)d_in[6];
  const float* b2  = (const float*)d_in[7];
  const float* W3  = (const float*)d_in[8];
  const float* b3  = (const float*)d_in[9];

  // Workspace layout (~778 KB)
  char* ws = (char*)d_ws;
  int*    fpsIdx = (int*)(ws);                 // 8192*4        = 32768
  float*  ctr    = (float*)(ws + 32768);       // 8192*3*4      = 98304   (ends 131072)
  __bf16* W1t    = (__bf16*)(ws + 131072);     // 128*96*2      = 24576   (ends 155648)
  __bf16* W2t    = (__bf16*)(ws + 155648);     // 128*128*2     = 32768   (ends 188416)
  __bf16* W3t    = (__bf16*)(ws + 188416);     // 256*128*2     = 65536   (ends 253952)
  float4* pos4   = (float4*)(ws + 253952);     // 32768*16      = 524288  (ends 778240)

  float* outX = (float*)d_out;                 // [8192,256]
  float* outP = outX + (long)EE * F3;          // [8192,3]
  float* outB = outP + (long)EE * 3;           // [8192]
  float* outS = outB + EE;                     // [8192]

  // blocks: 8 FPS + 120 wprep + 64 posp
  fps_prep_kernel<<<192, 512, 0, stream>>>(pos, W1, W2, W3,
                                           fpsIdx, ctr, W1t, W2t, W3t, pos4);
  mlp_kernel<<<EE, 512, 0, stream>>>(x, pos4, ctr, fpsIdx, W1t, W2t, W3t,
                                     b1, b2, b3, outX, outP, outB, outS);
}

// Round 9
// 866.651 us; speedup vs baseline: 1.9887x; 1.4827x over previous
//
#include <hip/hip_runtime.h>
#include <stdint.h>

#define BB 8
#define NN 4096
#define CC 64
#define MM 1024
#define EE (BB*MM)   // 8192 centroids
#define KK 64        // max neighbors
#define F3 256       // output channels
#define SM 104       // msg LDS stride (elements), 16B-aligned rows
#define SH 136       // h LDS stride (elements), 16B-aligned rows
#define CAP 768      // candidate buffer

typedef __bf16 bf16x8 __attribute__((ext_vector_type(8)));
typedef float floatx4 __attribute__((ext_vector_type(4)));
typedef float floatx2 __attribute__((ext_vector_type(2)));

// ---- wave64 reductions via DPP ----
#define DPP_MAXSTEP(ctrl, rmask) { \
    unsigned o = (unsigned)__builtin_amdgcn_update_dpp(0, (int)v, ctrl, rmask, 0xf, false); \
    v = v > o ? v : o; }
__device__ __forceinline__ unsigned wave_umax_u32(unsigned v) {
  DPP_MAXSTEP(0x111, 0xf)
  DPP_MAXSTEP(0x112, 0xf)
  DPP_MAXSTEP(0x114, 0xf)
  DPP_MAXSTEP(0x118, 0xf)
  DPP_MAXSTEP(0x142, 0xa)
  DPP_MAXSTEP(0x143, 0xc)
  return (unsigned)__builtin_amdgcn_readlane((int)v, 63);
}
#define DPP_MINSTEP(ctrl, rmask) { \
    unsigned o = (unsigned)__builtin_amdgcn_update_dpp((int)0xffffffffu, (int)v, ctrl, rmask, 0xf, false); \
    v = v < o ? v : o; }
__device__ __forceinline__ unsigned wave_umin_u32(unsigned v) {
  DPP_MINSTEP(0x111, 0xf)
  DPP_MINSTEP(0x112, 0xf)
  DPP_MINSTEP(0x114, 0xf)
  DPP_MINSTEP(0x118, 0xf)
  DPP_MINSTEP(0x142, 0xa)
  DPP_MINSTEP(0x143, 0xc)
  return (unsigned)__builtin_amdgcn_readlane((int)v, 63);
}

// ---- FPS (blocks 0..7; R6 structure + pk-f32 math) + wprep (8..127) + pos4 (128..191) ----
__global__ __launch_bounds__(512) void fps_prep_kernel(
    const float* __restrict__ pos,
    const float* __restrict__ W1, const float* __restrict__ W2, const float* __restrict__ W3,
    int* __restrict__ fpsIdx, float* __restrict__ ctr,
    __bf16* __restrict__ W1t, __bf16* __restrict__ W2t, __bf16* __restrict__ W3t,
    float4* __restrict__ pos4) {
  __shared__ float4 sP4[NN];                       // 64 KB
  __shared__ unsigned long long sRedK[2][8];
  const int blk = blockIdx.x;
  const int t = threadIdx.x;

  if (blk >= BB) {
    if (blk < 128) {                               // wprep: 61440 elements
      const int i0 = (blk - 8) * 512 + t;
      if (i0 < 128 * 96) {
        const int n = i0 / 96, k = i0 % 96;
        W1t[i0] = (k < 67) ? (__bf16)W1[k * 128 + n] : (__bf16)0.0f;
      } else if (i0 < 128 * 96 + 128 * 128) {
        const int i = i0 - 128 * 96;
        const int n = i / 128, k = i % 128;
        W2t[i] = (__bf16)W2[k * 128 + n];
      } else {
        const int i = i0 - (128 * 96 + 128 * 128);
        const int n = i / 128, k = i % 128;
        W3t[i] = (__bf16)W3[k * 256 + n];
      }
    } else {                                       // posp: 32768 points
      const int i = (blk - 128) * 512 + t;
      pos4[i] = make_float4(pos[(long)i * 3 + 0], pos[(long)i * 3 + 1],
                            pos[(long)i * 3 + 2], 0.0f);
    }
    return;
  }

  const int g = blk;
  const int lane = t & 63, wv = t >> 6;
  floatx2 p2x[4], p2y[4], p2z[4], mind2[4];
#pragma unroll
  for (int q = 0; q < 4; ++q) {
#pragma unroll
    for (int h = 0; h < 2; ++h) {
      const int p = t + (((q << 1) | h) << 9);
      const long base = ((long)g * NN + p) * 3;
      p2x[q][h] = pos[base + 0];
      p2y[q][h] = pos[base + 1];
      p2z[q][h] = pos[base + 2];
      mind2[q][h] = 1e10f;
      sP4[p] = make_float4(p2x[q][h], p2y[q][h], p2z[q][h], 0.0f);
    }
  }
  __syncthreads();
  float wx = sP4[0].x, wy = sP4[0].y, wz = sP4[0].z;
  int winI0 = 0, winI1 = 0;

  for (int s = 1; s < MM; ++s) {
    const floatx2 w2x = {wx, wx}, w2y = {wy, wy}, w2z = {wz, wz};
    float bv[4]; int bh[4];
    {
#pragma clang fp contract(off)
#pragma unroll
      for (int q = 0; q < 4; ++q) {
        const floatx2 dx = p2x[q] - w2x;
        const floatx2 dy = p2y[q] - w2y;
        const floatx2 dz = p2z[q] - w2z;
        const floatx2 d2 = (dx * dx + dy * dy) + dz * dz;   // np eval order, no fma
        floatx2 m = mind2[q];
        m[0] = fminf(m[0], d2[0]);
        m[1] = fminf(m[1], d2[1]);
        mind2[q] = m;
        // within-pair argmax (strict > keeps h=0 on tie -> smaller index)
        bv[q] = (m[1] > m[0]) ? m[1] : m[0];
        bh[q] = (m[1] > m[0]) ? 1 : 0;
      }
    }
    // depth-2 tree over q (strict > keeps earlier q -> smaller index)
    float v01 = bv[0]; int c01 = bh[0];
    if (bv[1] > v01) { v01 = bv[1]; c01 = 2 + bh[1]; }
    float v23 = bv[2]; int c23 = 4 + bh[2];
    if (bv[3] > v23) { v23 = bv[3]; c23 = 6 + bh[3]; }
    float vb = v01; int cb = c01;
    if (v23 > vb) { vb = v23; cb = c23; }
    const unsigned bb = __float_as_uint(vb);
    const unsigned bidx = (unsigned)(t + (cb << 9));

    const unsigned maxv = wave_umax_u32(bb);
    const unsigned cand = (bb == maxv) ? bidx : 0xffffffffu;
    const unsigned minidx = wave_umin_u32(cand);
    if (lane == 0)
      sRedK[s & 1][wv] = ((unsigned long long)maxv << 32) |
                         (unsigned long long)(~minidx);
    __syncthreads();
    unsigned long long kk = sRedK[s & 1][0];
#pragma unroll
    for (int w = 1; w < 8; ++w) {
      const unsigned long long kw = sRedK[s & 1][w];
      kk = kw > kk ? kw : kk;
    }
    const int widx = (int)(~(unsigned)kk);
    const float4 wp = sP4[widx];
    wx = wp.x; wy = wp.y; wz = wp.z;
    if (s == t)       winI0 = widx;
    if (s == t + 512) winI1 = widx;
  }
  // Epilogue: batched global writes (thread t owns steps t and t+512).
  {
    const long e0 = (long)g * MM + t;
    const float4 p0 = sP4[winI0];
    fpsIdx[e0] = winI0;
    ctr[e0 * 3 + 0] = p0.x; ctr[e0 * 3 + 1] = p0.y; ctr[e0 * 3 + 2] = p0.z;
    const long e1 = e0 + 512;
    const float4 p1 = sP4[winI1];
    fpsIdx[e1] = winI1;
    ctr[e1 * 3 + 0] = p1.x; ctr[e1 * 3 + 1] = p1.y; ctr[e1 * 3 + 2] = p1.z;
  }
}

// ---- Fused radius-search + rank-top-K + gather + 3-layer MLP (MFMA) + masked max ----
__global__ __launch_bounds__(512) void mlp_kernel(const float* __restrict__ x,
    const float4* __restrict__ pos4, const float* __restrict__ ctr,
    const int* __restrict__ fpsIdx,
    const __bf16* __restrict__ W1t, const __bf16* __restrict__ W2t,
    const __bf16* __restrict__ W3t,
    const float* __restrict__ b1, const float* __restrict__ b2,
    const float* __restrict__ b3,
    float* __restrict__ outX, float* __restrict__ outP,
    float* __restrict__ outB, float* __restrict__ outS) {
  __shared__ __align__(16) __bf16 sMsg[64 * SM];   // 13312 B; overlays sDI (6144 B)
  __shared__ __align__(16) __bf16 sH[64 * SH];     // 17408 B
  __shared__ int sSel[KK];
  __shared__ int sCnt;
  unsigned long long* sDI = (unsigned long long*)sMsg;  // [CAP] packed (d2bits<<32 | idx)

  const int e = blockIdx.x;
  const int t = threadIdx.x;
  const int b = e >> 10;
  const int lane = t & 63, wv = t >> 6;

  if (t == 0) sCnt = 0;
  const float cx = ctr[(long)e * 3 + 0];
  const float cy = ctr[(long)e * 3 + 1];
  const float cz = ctr[(long)e * 3 + 2];
  if (t < 3) outP[(long)e * 3 + t] = ctr[(long)e * 3 + t];
  if (t == 3) { outB[e] = (float)b; outS[e] = (float)(b * NN + fpsIdx[e]); }
  const float R2 = (float)(0.2 * 0.2);
  __syncthreads();

  // Phase A: scan 4096 points (float4 loads); ballot-compact candidates to LDS.
#pragma unroll
  for (int q = 0; q < NN / 512; ++q) {
    const int p = t + q * 512;
    const float4 P = pos4[b * NN + p];
    const float dx = __fsub_rn(cx, P.x);
    const float dy = __fsub_rn(cy, P.y);
    const float dz = __fsub_rn(cz, P.z);
    const float d2 = __fadd_rn(__fadd_rn(__fmul_rn(dx, dx), __fmul_rn(dy, dy)), __fmul_rn(dz, dz));
    const bool v = d2 < R2;
    const unsigned long long mask = __ballot(v);
    int wbase = 0;
    if (lane == 0 && mask) wbase = atomicAdd(&sCnt, (int)__popcll(mask));
    wbase = __shfl(wbase, 0);
    if (v) {
      const int off = wbase + (int)__popcll(mask & ((1ull << lane) - 1ull));
      if (off < CAP)
        sDI[off] = ((unsigned long long)__float_as_uint(d2) << 32) | (unsigned)p;
    }
  }
  __syncthreads();
  int cnt = sCnt; cnt = cnt > CAP ? CAP : cnt;
  const int nsel = cnt < KK ? cnt : KK;

  // Phase B: parallel rank selection. rank(i) = #{j : key_j < key_i}; keep rank<K.
  for (int i = t; i < cnt; i += 512) {
    const unsigned long long my = sDI[i];
    int rank = 0;
#pragma unroll 8
    for (int j = 0; j < cnt; ++j) rank += (sDI[j] < my) ? 1 : 0;
    if (rank < KK) sSel[rank] = (int)(unsigned)(my & 0xffffffffu);
  }
  __syncthreads();
  cnt = nsel;

  // Phase C: stage msg tile [64 x (64 feat | 3 dpos | zero-pad)] into LDS as bf16.
  {
    const int r = t >> 3, p = t & 7;
    float4 a = make_float4(0.f, 0.f, 0.f, 0.f), c4 = a;
    if (r < cnt) {
      const float* xr = x + (long)(b * NN + sSel[r]) * CC + p * 8;
      a  = *(const float4*)xr;
      c4 = *(const float4*)(xr + 4);
    }
    __bf16 o[8] = {(__bf16)a.x, (__bf16)a.y, (__bf16)a.z, (__bf16)a.w,
                   (__bf16)c4.x, (__bf16)c4.y, (__bf16)c4.z, (__bf16)c4.w};
    __syncthreads();  // Phase-B reads of sDI done before overwrite
    *(uint4*)&sMsg[r * SM + p * 8] = *(uint4*)o;
  }
  if (t < 64) {
    const int r = t;
    __bf16 d0 = (__bf16)0.0f, d1 = (__bf16)0.0f, d2v = (__bf16)0.0f;
    if (r < cnt) {
      const float4 P = pos4[b * NN + sSel[r]];
      d0  = (__bf16)__fsub_rn(P.x, cx);
      d1  = (__bf16)__fsub_rn(P.y, cy);
      d2v = (__bf16)__fsub_rn(P.z, cz);
    }
    sMsg[r * SM + 64] = d0;
    sMsg[r * SM + 65] = d1;
    sMsg[r * SM + 66] = d2v;
    for (int c = 67; c < SM; ++c) sMsg[r * SM + c] = (__bf16)0.0f;
  }
  __syncthreads();

  const int l15 = lane & 15, quad = lane >> 4;
  // ---- layer 1: [64 x 96] @ [96 x 128] -> sH ----
  {
    floatx4 acc[4] = {};
    const __bf16* wrow = W1t + (wv * 16 + l15) * 96;
#pragma unroll
    for (int ks = 0; ks < 3; ++ks) {
      const bf16x8 bfrag = *(const bf16x8*)(wrow + ks * 32 + quad * 8);
#pragma unroll
      for (int mt = 0; mt < 4; ++mt) {
        const bf16x8 afrag = *(const bf16x8*)&sMsg[(mt * 16 + l15) * SM + ks * 32 + quad * 8];
        acc[mt] = __builtin_amdgcn_mfma_f32_16x16x32_bf16(afrag, bfrag, acc[mt], 0, 0, 0);
      }
    }
    const int col = wv * 16 + l15;
    const float bias = b1[col];
#pragma unroll
    for (int mt = 0; mt < 4; ++mt)
#pragma unroll
      for (int rg = 0; rg < 4; ++rg) {
        const int row = mt * 16 + quad * 4 + rg;
        float v = acc[mt][rg] + bias;
        v = v > 0.0f ? v : 0.0f;
        sH[row * SH + col] = (__bf16)v;
      }
  }
  __syncthreads();
  // ---- layer 2: [64 x 128] @ [128 x 128], IN PLACE on sH ----
  {
    floatx4 acc[4] = {};
    const __bf16* wrow = W2t + (wv * 16 + l15) * 128;
#pragma unroll
    for (int ks = 0; ks < 4; ++ks) {
      const bf16x8 bfrag = *(const bf16x8*)(wrow + ks * 32 + quad * 8);
#pragma unroll
      for (int mt = 0; mt < 4; ++mt) {
        const bf16x8 afrag = *(const bf16x8*)&sH[(mt * 16 + l15) * SH + ks * 32 + quad * 8];
        acc[mt] = __builtin_amdgcn_mfma_f32_16x16x32_bf16(afrag, bfrag, acc[mt], 0, 0, 0);
      }
    }
    __syncthreads();
    const int col = wv * 16 + l15;
    const float bias = b2[col];
#pragma unroll
    for (int mt = 0; mt < 4; ++mt)
#pragma unroll
      for (int rg = 0; rg < 4; ++rg) {
        const int row = mt * 16 + quad * 4 + rg;
        float v = acc[mt][rg] + bias;
        v = v > 0.0f ? v : 0.0f;
        sH[row * SH + col] = (__bf16)v;
      }
  }
  __syncthreads();
  // ---- layer 3: [64 x 128] @ [128 x 256]; fused masked column max ----
  {
    floatx4 acc[2][4] = {};
#pragma unroll
    for (int ks = 0; ks < 4; ++ks) {
      bf16x8 afrag[4];
#pragma unroll
      for (int mt = 0; mt < 4; ++mt)
        afrag[mt] = *(const bf16x8*)&sH[(mt * 16 + l15) * SH + ks * 32 + quad * 8];
#pragma unroll
      for (int i = 0; i < 2; ++i) {
        const bf16x8 bfrag = *(const bf16x8*)(W3t + ((wv * 2 + i) * 16 + l15) * 128 + ks * 32 + quad * 8);
#pragma unroll
        for (int mt = 0; mt < 4; ++mt)
          acc[i][mt] = __builtin_amdgcn_mfma_f32_16x16x32_bf16(afrag[mt], bfrag, acc[i][mt], 0, 0, 0);
      }
    }
#pragma unroll
    for (int i = 0; i < 2; ++i) {
      const int col = (wv * 2 + i) * 16 + l15;
      const float bias = b3[col];
      float mx = 0.0f;  // centroid itself in-radius => cnt>=1; ReLU >= 0
#pragma unroll
      for (int mt = 0; mt < 4; ++mt)
#pragma unroll
        for (int rg = 0; rg < 4; ++rg) {
          const int row = mt * 16 + quad * 4 + rg;
          float v = acc[i][mt][rg] + bias;
          v = v > 0.0f ? v : 0.0f;
          if (row < cnt) mx = fmaxf(mx, v);
        }
      mx = fmaxf(mx, __shfl_xor(mx, 16));
      mx = fmaxf(mx, __shfl_xor(mx, 32));
      if (quad == 0) outX[(long)e * F3 + col] = mx;
    }
  }
}

extern "C" void kernel_launch(void* const* d_in, const int* in_sizes, int n_in,
                              void* d_out, int out_size, void* d_ws, size_t ws_size,
                              hipStream_t stream) {
  const float* x   = (const float*)d_in[0];
  const float* pos = (const float*)d_in[1];
  const float* W1  = (const float*)d_in[4];
  const float* b1  = (const float*)d_in[5];
  const float* W2  = (const float*)d_in[6];
  const float* b2  = (const float*)d_in[7];
  const float* W3  = (const float*)d_in[8];
  const float* b3  = (const float*)d_in[9];

  // Workspace layout (~778 KB)
  char* ws = (char*)d_ws;
  int*    fpsIdx = (int*)(ws);                 // 8192*4        = 32768
  float*  ctr    = (float*)(ws + 32768);       // 8192*3*4      = 98304   (ends 131072)
  __bf16* W1t    = (__bf16*)(ws + 131072);     // 128*96*2      = 24576   (ends 155648)
  __bf16* W2t    = (__bf16*)(ws + 155648);     // 128*128*2     = 32768   (ends 188416)
  __bf16* W3t    = (__bf16*)(ws + 188416);     // 256*128*2     = 65536   (ends 253952)
  float4* pos4   = (float4*)(ws + 253952);     // 32768*16      = 524288  (ends 778240)

  float* outX = (float*)d_out;                 // [8192,256]
  float* outP = outX + (long)EE * F3;          // [8192,3]
  float* outB = outP + (long)EE * 3;           // [8192]
  float* outS = outB + EE;                     // [8192]

  // blocks: 8 FPS + 120 wprep + 64 posp
  fps_prep_kernel<<<192, 512, 0, stream>>>(pos, W1, W2, W3,
                                           fpsIdx, ctr, W1t, W2t, W3t, pos4);
  mlp_kernel<<<EE, 512, 0, stream>>>(x, pos4, ctr, fpsIdx, W1t, W2t, W3t,
                                     b1, b2, b3, outX, outP, outB, outS);
}